// Round 3
// baseline (2965.364 us; speedup 1.0000x reference)
//
#include <hip/hip_runtime.h>
#include <math.h>

#define NT 4096
#define DM 1152
#define NH 16
#define DH 72
#define KRET 1638
#define NPR (NT - KRET)
#define KS 4
#define SCALE 0.11785113019775793f
#define RSPLIT 2048.0f
#define INV_RSPLIT 4.8828125e-4f

typedef __attribute__((ext_vector_type(8))) short bf16x8;
typedef _Float16 f16;
typedef __attribute__((ext_vector_type(8))) _Float16 f16x8;
typedef __attribute__((ext_vector_type(4))) float f32x4;
typedef unsigned short ushort_t;

__device__ inline ushort_t f2b(float f) {
    union { float f; unsigned int u; } v; v.f = f;
    unsigned int u = v.u;
    return (ushort_t)((u + 0x7FFFu + ((u >> 16) & 1u)) >> 16);
}

// ---------- split x into fp16 hi/lo(x2048) planes + bf16 copy ----------------
__global__ __launch_bounds__(256) void split_x(
    const float* __restrict__ in, f16* __restrict__ x0, f16* __restrict__ x1,
    ushort_t* __restrict__ xb, int nElem)
{
    int i = blockIdx.x * 256 + threadIdx.x;
    int stride = gridDim.x * 256;
    for (; i < nElem; i += stride) {
        float v = in[i];
        f16 h0 = (f16)v;
        float res = (v - (float)h0) * RSPLIT;
        x0[i] = h0;
        x1[i] = (f16)res;
        xb[i] = f2b(v);
    }
}

// ---------- transpose W into fp16 hi/lo(x2048) planes ------------------------
__global__ __launch_bounds__(256) void transposeW_split(
    const float* __restrict__ W, f16* __restrict__ T0, f16* __restrict__ T1, int n)
{
    __shared__ float t[32][33];
    int bx = blockIdx.x * 32, by = blockIdx.y * 32;
    int tx = threadIdx.x & 31, ty = threadIdx.x >> 5;
    for (int i = ty; i < 32; i += 8)
        t[i][tx] = W[(size_t)(by + i) * n + bx + tx];
    __syncthreads();
    for (int i = ty; i < 32; i += 8) {
        float v = t[tx][i];
        f16 h0 = (f16)v;
        float res = (v - (float)h0) * RSPLIT;
        T0[(size_t)(bx + i) * n + by + tx] = h0;
        T1[(size_t)(bx + i) * n + by + tx] = (f16)res;
    }
}

// ---------- transpose W into bf16 (V / O projection path) --------------------
__global__ __launch_bounds__(256) void transposeW_bf16(
    const float* __restrict__ W, ushort_t* __restrict__ WT, int n)
{
    __shared__ ushort_t t[32][33];
    int bx = blockIdx.x * 32, by = blockIdx.y * 32;
    int tx = threadIdx.x & 31, ty = threadIdx.x >> 5;
    for (int i = ty; i < 32; i += 8)
        t[i][tx] = f2b(W[(size_t)(by + i) * n + bx + tx]);
    __syncthreads();
    for (int i = ty; i < 32; i += 8)
        WT[(size_t)(bx + i) * n + by + tx] = t[tx][i];
}

__global__ __launch_bounds__(256) void transposeB16(
    const ushort_t* __restrict__ in, ushort_t* __restrict__ out,
    int rows, int cols)
{
    __shared__ ushort_t t[32][33];
    int bx = blockIdx.x * 32, by = blockIdx.y * 32;
    int tx = threadIdx.x & 31, ty = threadIdx.x >> 5;
    for (int i = ty; i < 32; i += 8)
        t[i][tx] = in[(size_t)(by + i) * cols + bx + tx];
    __syncthreads();
    for (int i = ty; i < 32; i += 8)
        out[(size_t)(bx + i) * rows + by + tx] = t[tx][i];
}

// ---------- fp32-quality projection via 3-term split-fp16 MFMA ---------------
// C = A[MxK] @ BT[NxK]^T ; A,B given as hi + lo/2048 fp16 planes.
// Output written directly as hi/lo split planes (for the QK^T consumer).
__global__ __launch_bounds__(256) void proj_split(
    const f16* __restrict__ A0, const f16* __restrict__ A1,
    const f16* __restrict__ B0, const f16* __restrict__ B1,
    f16* __restrict__ Q0, f16* __restrict__ Q1)
{
    const int tid = threadIdx.x;
    const int wave = tid >> 6, lane = tid & 63;
    const int r = lane & 15, g = lane >> 4;
    const int row0 = blockIdx.y * 64 + wave * 16;
    const int col0 = blockIdx.x * 64;
    const f16* a0r = A0 + (size_t)(row0 + r) * DM;
    const f16* a1r = A1 + (size_t)(row0 + r) * DM;
    f32x4 accM[4] = {}, accC[4] = {};
    for (int k0 = 0; k0 < DM; k0 += 32) {
        f16x8 a0 = *(const f16x8*)(a0r + k0 + g * 8);
        f16x8 a1 = *(const f16x8*)(a1r + k0 + g * 8);
#pragma unroll
        for (int t = 0; t < 4; ++t) {
            size_t bo = (size_t)(col0 + t * 16 + r) * DM + k0 + g * 8;
            f16x8 b0 = *(const f16x8*)(B0 + bo);
            f16x8 b1 = *(const f16x8*)(B1 + bo);
            accM[t] = __builtin_amdgcn_mfma_f32_16x16x32_f16(a0, b0, accM[t], 0, 0, 0);
            accC[t] = __builtin_amdgcn_mfma_f32_16x16x32_f16(a0, b1, accC[t], 0, 0, 0);
            accC[t] = __builtin_amdgcn_mfma_f32_16x16x32_f16(a1, b0, accC[t], 0, 0, 0);
        }
    }
#pragma unroll
    for (int t = 0; t < 4; ++t) {
        int col = col0 + t * 16 + r;
#pragma unroll
        for (int j = 0; j < 4; ++j) {
            int row = row0 + g * 4 + j;
            float v = accM[t][j] + accC[t][j] * INV_RSPLIT;
            f16 h0 = (f16)v;
            float res = (v - (float)h0) * RSPLIT;
            Q0[(size_t)row * DM + col] = h0;
            Q1[(size_t)row * DM + col] = (f16)res;
        }
    }
}

// ---------- S = scale * q_h k_h^T via 3-term split-fp16 MFMA -----------------
__global__ __launch_bounds__(256) void qk_split(
    const f16* __restrict__ Q0, const f16* __restrict__ Q1,
    const f16* __restrict__ K0, const f16* __restrict__ K1,
    float* __restrict__ S, int head)
{
    const int tid = threadIdx.x;
    const int wave = tid >> 6, lane = tid & 63;
    const int r = lane & 15, g = lane >> 4;
    const int row0 = blockIdx.y * 64 + wave * 16;
    const int col0 = blockIdx.x * 64;
    const int hb = head * DH;
    const f16* q0r = Q0 + (size_t)(row0 + r) * DM + hb;
    const f16* q1r = Q1 + (size_t)(row0 + r) * DM + hb;
    f32x4 accM[4] = {}, accC[4] = {};
#pragma unroll
    for (int ks = 0; ks < 3; ++ks) {
        const int k0 = ks * 32;
        const bool valid = (ks < 2) || (g == 0);   // head dim 72 = 32+32+8
        f16x8 a0 = {}, a1 = {};
        if (valid) {
            a0 = *(const f16x8*)(q0r + k0 + g * 8);
            a1 = *(const f16x8*)(q1r + k0 + g * 8);
        }
#pragma unroll
        for (int t = 0; t < 4; ++t) {
            f16x8 b0 = {}, b1 = {};
            if (valid) {
                size_t bo = (size_t)(col0 + t * 16 + r) * DM + hb + k0 + g * 8;
                b0 = *(const f16x8*)(K0 + bo);
                b1 = *(const f16x8*)(K1 + bo);
            }
            accM[t] = __builtin_amdgcn_mfma_f32_16x16x32_f16(a0, b0, accM[t], 0, 0, 0);
            accC[t] = __builtin_amdgcn_mfma_f32_16x16x32_f16(a0, b1, accC[t], 0, 0, 0);
            accC[t] = __builtin_amdgcn_mfma_f32_16x16x32_f16(a1, b0, accC[t], 0, 0, 0);
        }
    }
#pragma unroll
    for (int t = 0; t < 4; ++t) {
        int col = col0 + t * 16 + r;
#pragma unroll
        for (int j = 0; j < 4; ++j) {
            int row = row0 + g * 4 + j;
            S[(size_t)row * NT + col] = (accM[t][j] + accC[t][j] * INV_RSPLIT) * SCALE;
        }
    }
}

// --- row softmax (float4): attn += P/16 fp32, P written bf16 in-place in S ---
__global__ __launch_bounds__(256) void softmax_acc(
    float* __restrict__ S, float* __restrict__ attn)
{
    __shared__ float4 row4[NT / 4];
    __shared__ float red[8];
    const int tid = threadIdx.x;
    float4* srow4 = (float4*)(S + (size_t)blockIdx.x * NT);
    float m = -INFINITY;
    for (int j = tid; j < NT / 4; j += 256) {
        float4 v = srow4[j];
        row4[j] = v;
        m = fmaxf(m, fmaxf(fmaxf(v.x, v.y), fmaxf(v.z, v.w)));
    }
#pragma unroll
    for (int o = 32; o; o >>= 1) m = fmaxf(m, __shfl_xor(m, o));
    if ((tid & 63) == 0) red[tid >> 6] = m;
    __syncthreads();
    m = fmaxf(fmaxf(red[0], red[1]), fmaxf(red[2], red[3]));
    float s = 0.f;
    for (int j = tid; j < NT / 4; j += 256) {
        float4 v = row4[j];
        float4 e;
        e.x = __expf(v.x - m); e.y = __expf(v.y - m);
        e.z = __expf(v.z - m); e.w = __expf(v.w - m);
        row4[j] = e;
        s += (e.x + e.y) + (e.z + e.w);
    }
#pragma unroll
    for (int o = 32; o; o >>= 1) s += __shfl_xor(s, o);
    if ((tid & 63) == 0) red[4 + (tid >> 6)] = s;
    __syncthreads();
    s = (red[4] + red[5]) + (red[6] + red[7]);
    const float inv = 1.0f / s;
    float4* arow4 = (float4*)(attn + (size_t)blockIdx.x * NT);
    uint2* pb = (uint2*)srow4;   // bf16 P packed into first half of the row
    for (int j = tid; j < NT / 4; j += 256) {
        float4 e = row4[j];
        float4 p;
        p.x = e.x * inv; p.y = e.y * inv; p.z = e.z * inv; p.w = e.w * inv;
        uint2 w;
        w.x = (unsigned)f2b(p.x) | ((unsigned)f2b(p.y) << 16);
        w.y = (unsigned)f2b(p.z) | ((unsigned)f2b(p.w) << 16);
        pb[j] = w;
        float4 a = arow4[j];
        a.x += p.x * 0.0625f; a.y += p.y * 0.0625f;
        a.z += p.z * 0.0625f; a.w += p.w * 0.0625f;
        arow4[j] = a;
    }
}

// ---------- bf16 MFMA GEMM (V projection / output projection) ----------------
__global__ __launch_bounds__(256) void gemm_mfma(
    const ushort_t* __restrict__ A, const ushort_t* __restrict__ BT,
    const float* __restrict__ bias, void* __restrict__ C, int cbf16,
    int M, int Nn, int K)
{
    const int tid = threadIdx.x;
    const int wave = tid >> 6, lane = tid & 63;
    const int r = lane & 15, g = lane >> 4;
    const int row0 = blockIdx.y * 64 + wave * 16;
    const int col0 = blockIdx.x * 64;
    const ushort_t* arow = A + (size_t)(row0 + r) * K;
    f32x4 acc[4] = {};
    for (int k0 = 0; k0 < K; k0 += 32) {
        bf16x8 a = *(const bf16x8*)(arow + k0 + g * 8);
#pragma unroll
        for (int t = 0; t < 4; ++t) {
            bf16x8 b = *(const bf16x8*)(BT + (size_t)(col0 + t * 16 + r) * K + k0 + g * 8);
            acc[t] = __builtin_amdgcn_mfma_f32_16x16x32_bf16(a, b, acc[t], 0, 0, 0);
        }
    }
#pragma unroll
    for (int t = 0; t < 4; ++t) {
        int col = col0 + t * 16 + r;
        float bv = bias ? bias[col] : 0.f;
#pragma unroll
        for (int j = 0; j < 4; ++j) {
            int row = row0 + g * 4 + j;
            float vv = acc[t][j] + bv;
            if (cbf16) ((ushort_t*)C)[(size_t)row * Nn + col] = f2b(vv);
            else       ((float*)C)[(size_t)row * Nn + col] = vv;
        }
    }
}

// ---------- O_h = P @ v_h via bf16 MFMA (k-split partials) -------------------
__global__ __launch_bounds__(256) void pv_mfma(
    const float* __restrict__ Sbuf, const ushort_t* __restrict__ vtb,
    float* __restrict__ part, int head)
{
    const int tid = threadIdx.x;
    const int wave = tid >> 6, lane = tid & 63;
    const int r = lane & 15, g = lane >> 4;
    const int row0 = blockIdx.x * 64 + wave * 16;
    const int k0base = blockIdx.y * (NT / KS);
    const int hb = head * DH;
    const ushort_t* arow = (const ushort_t*)(Sbuf + (size_t)(row0 + r) * NT);
    f32x4 acc[5] = {};
    for (int kk = 0; kk < NT / KS; kk += 32) {
        int k0 = k0base + kk;
        bf16x8 a = *(const bf16x8*)(arow + k0 + g * 8);
#pragma unroll
        for (int t = 0; t < 5; ++t) {
            int col = t * 16 + r;
            bf16x8 b = {};
            if (col < DH)
                b = *(const bf16x8*)(vtb + (size_t)(hb + col) * NT + k0 + g * 8);
            acc[t] = __builtin_amdgcn_mfma_f32_16x16x32_bf16(a, b, acc[t], 0, 0, 0);
        }
    }
    float* pp = part + (size_t)blockIdx.y * (NT * DH);
#pragma unroll
    for (int t = 0; t < 5; ++t) {
        int col = t * 16 + r;
        if (col < DH) {
#pragma unroll
            for (int j = 0; j < 4; ++j) {
                int row = row0 + g * 4 + j;
                pp[(size_t)row * DH + col] = acc[t][j];
            }
        }
    }
}

__global__ __launch_bounds__(256) void pv_reduce(
    const float* __restrict__ part, ushort_t* __restrict__ otmpb, int head)
{
    int idx = blockIdx.x * 256 + threadIdx.x;
    if (idx >= NT * DH) return;
    int row = idx / DH, col = idx - row * DH;
    float s = 0.f;
#pragma unroll
    for (int ks = 0; ks < KS; ++ks) s += part[(size_t)ks * (NT * DH) + idx];
    otmpb[(size_t)row * DM + head * DH + col] = f2b(s);
}

// ---------- pagerank power iteration (fp32, unchanged) -----------------------
__global__ __launch_bounds__(256) void init_dist(float* __restrict__ d)
{
    int t = blockIdx.x * 256 + threadIdx.x;
    if (t < NT) d[t] = 1.0f / NT;
}

__global__ __launch_bounds__(256) void power_a(
    const float* __restrict__ attn, const float* __restrict__ din,
    float* __restrict__ part)
{
    int j = blockIdx.x * 256 + threadIdx.x;
    int i0 = blockIdx.y * 128;
    float acc = 0.f;
    for (int i = i0; i < i0 + 128; ++i)
        acc += din[i] * attn[(size_t)i * NT + j];
    part[(size_t)blockIdx.y * NT + j] = acc;
}

__global__ __launch_bounds__(256) void power_b(
    const float* __restrict__ part, float* __restrict__ dout)
{
    int j = blockIdx.x * 256 + threadIdx.x;
    float acc = 0.f;
    for (int ib = 0; ib < 32; ++ib) acc += part[(size_t)ib * NT + j];
    dout[j] = acc;
}

// ---------- top-k via rank counting (jax tie rule) ---------------------------
__global__ __launch_bounds__(256) void rank_kernel(
    const float* __restrict__ imp, int* __restrict__ rank, int* __restrict__ prank)
{
    __shared__ float si[NT];
    for (int t = threadIdx.x; t < NT; t += 256) si[t] = imp[t];
    __syncthreads();
    int i = blockIdx.x * 256 + threadIdx.x;
    float mv = si[i];
    int r = 0, rp = 0;
    for (int j = 0; j < NT; ++j) {
        float vj = si[j];
        int tie_low = (vj == mv) && (j < i);
        r  += (vj > mv) || tie_low;
        rp += (vj < mv) || tie_low;
    }
    rank[i] = r;
    prank[i] = rp;
}

__global__ __launch_bounds__(256) void scatter_topk(
    const int* __restrict__ rank, const int* __restrict__ prank,
    float* __restrict__ out_imps, float* __restrict__ out_prune,
    int* __restrict__ imp_rows, int* __restrict__ prune_cols)
{
    __shared__ unsigned char fr[NT];
    __shared__ unsigned char fp[NT];
    for (int t = threadIdx.x; t < NT; t += 256) {
        fr[t] = rank[t] < KRET;
        fp[t] = prank[t] < NPR;
    }
    __syncthreads();
    int i = blockIdx.x * 256 + threadIdx.x;
    int cr = 0, cp = 0;
    for (int j = 0; j < i; ++j) { cr += fr[j]; cp += fp[j]; }
    if (fr[i]) { out_imps[cr] = (float)i; imp_rows[cr] = i; }
    if (fp[i]) { out_prune[cp] = (float)i; prune_cols[cp] = i; }
}

__global__ __launch_bounds__(256) void argmax_cols(
    const float* __restrict__ attn, const int* __restrict__ imp_rows,
    int* __restrict__ maxind)
{
    __shared__ int rows[KRET];
    for (int t = threadIdx.x; t < KRET; t += 256) rows[t] = imp_rows[t];
    __syncthreads();
    int j = blockIdx.x * 256 + threadIdx.x;
    float best = -INFINITY;
    int bi = 0;
    for (int r = 0; r < KRET; ++r) {
        float val = attn[(size_t)rows[r] * NT + j];
        if (val > best) { best = val; bi = r; }
    }
    maxind[j] = bi;
}

__global__ __launch_bounds__(256) void finalize(
    const float* __restrict__ dist, const int* __restrict__ prune_cols,
    const int* __restrict__ maxind, float* __restrict__ out_imp,
    float* __restrict__ out_simi)
{
    int t = blockIdx.x * 256 + threadIdx.x;
    if (t < NT) out_imp[t] = dist[t];
    if (t < NPR) out_simi[t] = (float)maxind[prune_cols[t]];
}

extern "C" void kernel_launch(void* const* d_in, const int* in_sizes, int n_in,
                              void* d_out, int out_size, void* d_ws, size_t ws_size,
                              hipStream_t stream)
{
    const float* x  = (const float*)d_in[0];
    const float* Wq = (const float*)d_in[1];
    const float* Wk = (const float*)d_in[2];
    const float* Wv = (const float*)d_in[3];
    const float* Wo = (const float*)d_in[4];
    const float* bo = (const float*)d_in[5];
    float* out = (float*)d_out;

    // ---- workspace layout (float units), ~200 MB with aliasing ----
    float* ws = (float*)d_ws;
    size_t off = 0;
    float* S    = ws + off; off += (size_t)NT * NT;        // 16.78M
    float* attn = ws + off; off += (size_t)NT * NT;        // 16.78M
    f16* Q0 = (f16*)(ws + off); off += ((size_t)NT * DM) / 2 * 2 / 2; // placeholder
    // recompute cleanly:
    off = (size_t)NT * NT * 2;
    Q0 = (f16*)(ws + off);                 // qs2: 2 planes fp16 [NT][DM]
    f16* Q1 = Q0 + (size_t)NT * DM;
    off += (size_t)NT * DM;                // 2 planes * NT*DM f16 = NT*DM floats
    f16* K0 = (f16*)(ws + off);
    f16* K1 = K0 + (size_t)NT * DM;
    off += (size_t)NT * DM;
    f16* X0 = (f16*)(ws + off);            // xs2: later vtb + otmpb
    f16* X1 = X0 + (size_t)NT * DM;
    float* xs2_base = ws + off;
    off += (size_t)NT * DM;
    f16* T0 = (f16*)(ws + off);            // WT2: later part
    f16* T1 = T0 + (size_t)DM * DM;
    float* wt2_base = ws + off;
    off += (size_t)DM * DM / 2 * 2 / 2 + (size_t)DM * DM / 2; // = DM*DM floats? no:
    // 2 planes * DM*DM f16 elems = DM*DM floats:
    off = (size_t)NT * NT * 2 + (size_t)NT * DM * 3 + (size_t)DM * DM;
    ushort_t* Wslot = (ushort_t*)(ws + off); off += ((size_t)DM * DM) / 2;
    float* dist0 = ws + off; off += NT;
    float* dist1 = ws + off; off += NT;
    float* partial = ws + off; off += 32 * NT;
    int* rank      = (int*)(ws + off); off += NT;
    int* prank     = (int*)(ws + off); off += NT;
    int* imp_rows  = (int*)(ws + off); off += 2048;
    int* prune_cols= (int*)(ws + off); off += 2560;
    int* maxind    = (int*)(ws + off); off += NT;

    // aliases
    ushort_t* xb   = (ushort_t*)S;                              // bf16 x (setup only)
    ushort_t* vb   = (ushort_t*)(S + (size_t)NT * DM / 2);      // bf16 v (setup only)
    ushort_t* vtb  = (ushort_t*)xs2_base;                       // bf16 v^T [DM][NT]
    ushort_t* otmpb= (ushort_t*)(xs2_base + (size_t)NT * DM / 2); // bf16 attn-out
    float* part    = wt2_base;                                  // fp32 [KS][NT][DH]

    // output layout
    float* out_out   = out;
    float* out_imp   = out + (size_t)NT * DM;
    float* out_imps  = out_imp + NT;
    float* out_prune = out_imps + KRET;
    float* out_simi  = out_prune + NPR;

    // ---- setup: splits + projections ----
    split_x<<<2048, 256, 0, stream>>>(x, X0, X1, xb, NT * DM);

    dim3 gT(DM / 32, DM / 32);
    dim3 gP(DM / 64, NT / 64);
    transposeW_split<<<gT, 256, 0, stream>>>(Wq, T0, T1, DM);
    proj_split<<<gP, 256, 0, stream>>>(X0, X1, T0, T1, Q0, Q1);
    transposeW_split<<<gT, 256, 0, stream>>>(Wk, T0, T1, DM);
    proj_split<<<gP, 256, 0, stream>>>(X0, X1, T0, T1, K0, K1);

    transposeW_bf16<<<gT, 256, 0, stream>>>(Wv, Wslot, DM);
    gemm_mfma<<<gP, 256, 0, stream>>>(xb, Wslot, nullptr, vb, 1, NT, DM, DM);
    transposeB16<<<dim3(DM / 32, NT / 32), 256, 0, stream>>>(vb, vtb, NT, DM);

    hipMemsetAsync(attn, 0, (size_t)NT * NT * sizeof(float), stream);

    // ---- per-head attention ----
    dim3 g2(NT / 64, NT / 64);
    for (int h = 0; h < NH; ++h) {
        qk_split<<<g2, 256, 0, stream>>>(Q0, Q1, K0, K1, S, h);
        softmax_acc<<<NT, 256, 0, stream>>>(S, attn);
        pv_mfma<<<dim3(NT / 64, KS), 256, 0, stream>>>(S, vtb, part, h);
        pv_reduce<<<(NT * DH) / 256, 256, 0, stream>>>(part, otmpb, h);
    }

    // ---- output projection ----
    transposeW_bf16<<<gT, 256, 0, stream>>>(Wo, Wslot, DM);
    gemm_mfma<<<gP, 256, 0, stream>>>(otmpb, Wslot, bo, out_out, 0, NT, DM, DM);

    // ---- pagerank + top-k (fp32, unchanged) ----
    init_dist<<<16, 256, 0, stream>>>(dist0);
    float* da = dist0;
    float* db = dist1;
    for (int it = 0; it < 5; ++it) {
        power_a<<<dim3(16, 32), 256, 0, stream>>>(attn, da, partial);
        power_b<<<16, 256, 0, stream>>>(partial, db);
        float* t = da; da = db; db = t;
    }

    rank_kernel<<<16, 256, 0, stream>>>(da, rank, prank);
    scatter_topk<<<16, 256, 0, stream>>>(rank, prank, out_imps, out_prune,
                                         imp_rows, prune_cols);
    argmax_cols<<<16, 256, 0, stream>>>(attn, imp_rows, maxind);
    finalize<<<16, 256, 0, stream>>>(da, prune_cols, maxind, out_imp, out_simi);
}

// Round 4
// 2129.419 us; speedup vs baseline: 1.3926x; 1.3926x over previous
//
#include <hip/hip_runtime.h>
#include <math.h>

#define NT 4096
#define DM 1152
#define NH 16
#define DH 72
#define KRET 1638
#define NPR (NT - KRET)
#define KS 4
#define SCALE 0.11785113019775793f
#define RSPLIT 2048.0f
#define INV_RSPLIT 4.8828125e-4f

typedef __attribute__((ext_vector_type(8))) short bf16x8;
typedef _Float16 f16;
typedef __attribute__((ext_vector_type(8))) _Float16 f16x8;
typedef __attribute__((ext_vector_type(4))) float f32x4;
typedef unsigned short ushort_t;

__device__ inline ushort_t f2b(float f) {
    union { float f; unsigned int u; } v; v.f = f;
    unsigned int u = v.u;
    return (ushort_t)((u + 0x7FFFu + ((u >> 16) & 1u)) >> 16);
}

// ---------- split x into fp16 hi/lo(x2048) planes + bf16 copy ----------------
__global__ __launch_bounds__(256) void split_x(
    const float* __restrict__ in, f16* __restrict__ x0, f16* __restrict__ x1,
    ushort_t* __restrict__ xb, int nElem)
{
    int i = blockIdx.x * 256 + threadIdx.x;
    int stride = gridDim.x * 256;
    for (; i < nElem; i += stride) {
        float v = in[i];
        f16 h0 = (f16)v;
        float res = (v - (float)h0) * RSPLIT;
        x0[i] = h0;
        x1[i] = (f16)res;
        xb[i] = f2b(v);
    }
}

// ---------- transpose W into fp16 hi/lo(x2048) planes ------------------------
__global__ __launch_bounds__(256) void transposeW_split(
    const float* __restrict__ W, f16* __restrict__ T0, f16* __restrict__ T1, int n)
{
    __shared__ float t[32][33];
    int bx = blockIdx.x * 32, by = blockIdx.y * 32;
    int tx = threadIdx.x & 31, ty = threadIdx.x >> 5;
    for (int i = ty; i < 32; i += 8)
        t[i][tx] = W[(size_t)(by + i) * n + bx + tx];
    __syncthreads();
    for (int i = ty; i < 32; i += 8) {
        float v = t[tx][i];
        f16 h0 = (f16)v;
        float res = (v - (float)h0) * RSPLIT;
        T0[(size_t)(bx + i) * n + by + tx] = h0;
        T1[(size_t)(bx + i) * n + by + tx] = (f16)res;
    }
}

// ---------- transpose W into bf16 (V / O projection path) --------------------
__global__ __launch_bounds__(256) void transposeW_bf16(
    const float* __restrict__ W, ushort_t* __restrict__ WT, int n)
{
    __shared__ ushort_t t[32][33];
    int bx = blockIdx.x * 32, by = blockIdx.y * 32;
    int tx = threadIdx.x & 31, ty = threadIdx.x >> 5;
    for (int i = ty; i < 32; i += 8)
        t[i][tx] = f2b(W[(size_t)(by + i) * n + bx + tx]);
    __syncthreads();
    for (int i = ty; i < 32; i += 8)
        WT[(size_t)(bx + i) * n + by + tx] = t[tx][i];
}

__global__ __launch_bounds__(256) void transposeB16(
    const ushort_t* __restrict__ in, ushort_t* __restrict__ out,
    int rows, int cols)
{
    __shared__ ushort_t t[32][33];
    int bx = blockIdx.x * 32, by = blockIdx.y * 32;
    int tx = threadIdx.x & 31, ty = threadIdx.x >> 5;
    for (int i = ty; i < 32; i += 8)
        t[i][tx] = in[(size_t)(by + i) * cols + bx + tx];
    __syncthreads();
    for (int i = ty; i < 32; i += 8)
        out[(size_t)(bx + i) * rows + by + tx] = t[tx][i];
}

// ---------- LDS-tiled fp32-quality projection (3-term split-f16 MFMA) --------
// C = A[4096xDM] @ BT[DMxDM]^T ; 128x64 tile, BK=32. Output re-split to planes.
__global__ __launch_bounds__(256) void proj_split2(
    const f16* __restrict__ A0, const f16* __restrict__ A1,
    const f16* __restrict__ B0, const f16* __restrict__ B1,
    f16* __restrict__ Q0, f16* __restrict__ Q1)
{
    __shared__ __align__(16) f16 As0[128][40];
    __shared__ __align__(16) f16 As1[128][40];
    __shared__ __align__(16) f16 Bs0[64][40];
    __shared__ __align__(16) f16 Bs1[64][40];
    const int tid = threadIdx.x;
    const int wave = tid >> 6, lane = tid & 63;
    const int r = lane & 15, g = lane >> 4;
    const int row0 = blockIdx.y * 128;
    const int col0 = blockIdx.x * 64;
    f32x4 accM[2][4] = {}, accC[2][4] = {};
    for (int k0 = 0; k0 < DM; k0 += 32) {
        for (int idx = tid; idx < 128 * 4; idx += 256) {
            int row = idx >> 2, c = idx & 3;
            size_t src = (size_t)(row0 + row) * DM + k0 + c * 8;
            *(f16x8*)&As0[row][c * 8] = *(const f16x8*)(A0 + src);
            *(f16x8*)&As1[row][c * 8] = *(const f16x8*)(A1 + src);
        }
        for (int idx = tid; idx < 64 * 4; idx += 256) {
            int row = idx >> 2, c = idx & 3;
            size_t src = (size_t)(col0 + row) * DM + k0 + c * 8;
            *(f16x8*)&Bs0[row][c * 8] = *(const f16x8*)(B0 + src);
            *(f16x8*)&Bs1[row][c * 8] = *(const f16x8*)(B1 + src);
        }
        __syncthreads();
        f16x8 a0[2], a1[2], b0[4], b1[4];
#pragma unroll
        for (int rf = 0; rf < 2; ++rf) {
            a0[rf] = *(const f16x8*)&As0[wave * 32 + rf * 16 + r][g * 8];
            a1[rf] = *(const f16x8*)&As1[wave * 32 + rf * 16 + r][g * 8];
        }
#pragma unroll
        for (int cf = 0; cf < 4; ++cf) {
            b0[cf] = *(const f16x8*)&Bs0[cf * 16 + r][g * 8];
            b1[cf] = *(const f16x8*)&Bs1[cf * 16 + r][g * 8];
        }
#pragma unroll
        for (int rf = 0; rf < 2; ++rf)
#pragma unroll
            for (int cf = 0; cf < 4; ++cf) {
                accM[rf][cf] = __builtin_amdgcn_mfma_f32_16x16x32_f16(a0[rf], b0[cf], accM[rf][cf], 0, 0, 0);
                accC[rf][cf] = __builtin_amdgcn_mfma_f32_16x16x32_f16(a0[rf], b1[cf], accC[rf][cf], 0, 0, 0);
                accC[rf][cf] = __builtin_amdgcn_mfma_f32_16x16x32_f16(a1[rf], b0[cf], accC[rf][cf], 0, 0, 0);
            }
        __syncthreads();
    }
#pragma unroll
    for (int rf = 0; rf < 2; ++rf)
#pragma unroll
        for (int cf = 0; cf < 4; ++cf) {
            int col = col0 + cf * 16 + r;
#pragma unroll
            for (int j = 0; j < 4; ++j) {
                int row = row0 + wave * 32 + rf * 16 + g * 4 + j;
                float v = accM[rf][cf][j] + accC[rf][cf][j] * INV_RSPLIT;
                f16 h0 = (f16)v;
                float res = (v - (float)h0) * RSPLIT;
                Q0[(size_t)row * DM + col] = h0;
                Q1[(size_t)row * DM + col] = (f16)res;
            }
        }
}

// ---------- LDS-tiled S = scale * q_h k_h^T (3-term split-f16 MFMA) ----------
// 64x64 tile per block; K=72 zero-padded to 96 in LDS; whole tiles staged once.
__global__ __launch_bounds__(256) void qk_split2(
    const f16* __restrict__ Q0, const f16* __restrict__ Q1,
    const f16* __restrict__ K0, const f16* __restrict__ K1,
    float* __restrict__ S, int head)
{
    __shared__ __align__(16) f16 Qs0[64][104];
    __shared__ __align__(16) f16 Qs1[64][104];
    __shared__ __align__(16) f16 Ks0[64][104];
    __shared__ __align__(16) f16 Ks1[64][104];
    const int tid = threadIdx.x;
    const int wave = tid >> 6, lane = tid & 63;
    const int r = lane & 15, g = lane >> 4;
    const int row0 = blockIdx.y * 64;
    const int col0 = blockIdx.x * 64;
    const int hb = head * DH;
    for (int idx = tid; idx < 64 * 9; idx += 256) {
        int row = idx / 9, c = idx - row * 9;
        size_t sq = (size_t)(row0 + row) * DM + hb + c * 8;
        size_t sk = (size_t)(col0 + row) * DM + hb + c * 8;
        *(f16x8*)&Qs0[row][c * 8] = *(const f16x8*)(Q0 + sq);
        *(f16x8*)&Qs1[row][c * 8] = *(const f16x8*)(Q1 + sq);
        *(f16x8*)&Ks0[row][c * 8] = *(const f16x8*)(K0 + sk);
        *(f16x8*)&Ks1[row][c * 8] = *(const f16x8*)(K1 + sk);
    }
    for (int idx = tid; idx < 64 * 3; idx += 256) {
        int row = idx / 3, c = idx - row * 3;
        f16x8 z = {};
        *(f16x8*)&Qs0[row][72 + c * 8] = z;
        *(f16x8*)&Qs1[row][72 + c * 8] = z;
        *(f16x8*)&Ks0[row][72 + c * 8] = z;
        *(f16x8*)&Ks1[row][72 + c * 8] = z;
    }
    __syncthreads();
    f32x4 accM[4] = {}, accC[4] = {};
#pragma unroll
    for (int ks = 0; ks < 3; ++ks) {
        const int kb = ks * 32 + g * 8;
        f16x8 a0 = *(const f16x8*)&Qs0[wave * 16 + r][kb];
        f16x8 a1 = *(const f16x8*)&Qs1[wave * 16 + r][kb];
#pragma unroll
        for (int cf = 0; cf < 4; ++cf) {
            f16x8 b0 = *(const f16x8*)&Ks0[cf * 16 + r][kb];
            f16x8 b1 = *(const f16x8*)&Ks1[cf * 16 + r][kb];
            accM[cf] = __builtin_amdgcn_mfma_f32_16x16x32_f16(a0, b0, accM[cf], 0, 0, 0);
            accC[cf] = __builtin_amdgcn_mfma_f32_16x16x32_f16(a0, b1, accC[cf], 0, 0, 0);
            accC[cf] = __builtin_amdgcn_mfma_f32_16x16x32_f16(a1, b0, accC[cf], 0, 0, 0);
        }
    }
#pragma unroll
    for (int cf = 0; cf < 4; ++cf) {
        int col = col0 + cf * 16 + r;
#pragma unroll
        for (int j = 0; j < 4; ++j) {
            int row = row0 + wave * 16 + g * 4 + j;
            S[(size_t)row * NT + col] = (accM[cf][j] + accC[cf][j] * INV_RSPLIT) * SCALE;
        }
    }
}

// ---------- LDS-tiled bf16 MFMA GEMM (V / O projections) ---------------------
__global__ __launch_bounds__(256) void gemm_bf16_lds(
    const ushort_t* __restrict__ A, const ushort_t* __restrict__ BT,
    const float* __restrict__ bias, void* __restrict__ C, int cbf16,
    int Nn, int K)
{
    __shared__ __align__(16) ushort_t As[128][40];
    __shared__ __align__(16) ushort_t Bs[64][40];
    const int tid = threadIdx.x;
    const int wave = tid >> 6, lane = tid & 63;
    const int r = lane & 15, g = lane >> 4;
    const int row0 = blockIdx.y * 128;
    const int col0 = blockIdx.x * 64;
    f32x4 acc[2][4] = {};
    for (int k0 = 0; k0 < K; k0 += 32) {
        for (int idx = tid; idx < 128 * 4; idx += 256) {
            int row = idx >> 2, c = idx & 3;
            *(bf16x8*)&As[row][c * 8] = *(const bf16x8*)(A + (size_t)(row0 + row) * K + k0 + c * 8);
        }
        for (int idx = tid; idx < 64 * 4; idx += 256) {
            int row = idx >> 2, c = idx & 3;
            *(bf16x8*)&Bs[row][c * 8] = *(const bf16x8*)(BT + (size_t)(col0 + row) * K + k0 + c * 8);
        }
        __syncthreads();
        bf16x8 a[2], b[4];
#pragma unroll
        for (int rf = 0; rf < 2; ++rf)
            a[rf] = *(const bf16x8*)&As[wave * 32 + rf * 16 + r][g * 8];
#pragma unroll
        for (int cf = 0; cf < 4; ++cf)
            b[cf] = *(const bf16x8*)&Bs[cf * 16 + r][g * 8];
#pragma unroll
        for (int rf = 0; rf < 2; ++rf)
#pragma unroll
            for (int cf = 0; cf < 4; ++cf)
                acc[rf][cf] = __builtin_amdgcn_mfma_f32_16x16x32_bf16(a[rf], b[cf], acc[rf][cf], 0, 0, 0);
        __syncthreads();
    }
#pragma unroll
    for (int rf = 0; rf < 2; ++rf)
#pragma unroll
        for (int cf = 0; cf < 4; ++cf) {
            int col = col0 + cf * 16 + r;
            float bv = bias ? bias[col] : 0.f;
#pragma unroll
            for (int j = 0; j < 4; ++j) {
                int row = row0 + wave * 32 + rf * 16 + g * 4 + j;
                float vv = acc[rf][cf][j] + bv;
                if (cbf16) ((ushort_t*)C)[(size_t)row * Nn + col] = f2b(vv);
                else       ((float*)C)[(size_t)row * Nn + col] = vv;
            }
        }
}

// --- row softmax (float4): attn += P/16 fp32, P written bf16 in-place in S ---
__global__ __launch_bounds__(256) void softmax_acc(
    float* __restrict__ S, float* __restrict__ attn)
{
    __shared__ float4 row4[NT / 4];
    __shared__ float red[8];
    const int tid = threadIdx.x;
    float4* srow4 = (float4*)(S + (size_t)blockIdx.x * NT);
    float m = -INFINITY;
    for (int j = tid; j < NT / 4; j += 256) {
        float4 v = srow4[j];
        row4[j] = v;
        m = fmaxf(m, fmaxf(fmaxf(v.x, v.y), fmaxf(v.z, v.w)));
    }
#pragma unroll
    for (int o = 32; o; o >>= 1) m = fmaxf(m, __shfl_xor(m, o));
    if ((tid & 63) == 0) red[tid >> 6] = m;
    __syncthreads();
    m = fmaxf(fmaxf(red[0], red[1]), fmaxf(red[2], red[3]));
    float s = 0.f;
    for (int j = tid; j < NT / 4; j += 256) {
        float4 v = row4[j];
        float4 e;
        e.x = __expf(v.x - m); e.y = __expf(v.y - m);
        e.z = __expf(v.z - m); e.w = __expf(v.w - m);
        row4[j] = e;
        s += (e.x + e.y) + (e.z + e.w);
    }
#pragma unroll
    for (int o = 32; o; o >>= 1) s += __shfl_xor(s, o);
    if ((tid & 63) == 0) red[4 + (tid >> 6)] = s;
    __syncthreads();
    s = (red[4] + red[5]) + (red[6] + red[7]);
    const float inv = 1.0f / s;
    float4* arow4 = (float4*)(attn + (size_t)blockIdx.x * NT);
    uint2* pb = (uint2*)srow4;   // bf16 P packed into first half of the row
    for (int j = tid; j < NT / 4; j += 256) {
        float4 e = row4[j];
        float4 p;
        p.x = e.x * inv; p.y = e.y * inv; p.z = e.z * inv; p.w = e.w * inv;
        uint2 w;
        w.x = (unsigned)f2b(p.x) | ((unsigned)f2b(p.y) << 16);
        w.y = (unsigned)f2b(p.z) | ((unsigned)f2b(p.w) << 16);
        pb[j] = w;
        float4 a = arow4[j];
        a.x += p.x * 0.0625f; a.y += p.y * 0.0625f;
        a.z += p.z * 0.0625f; a.w += p.w * 0.0625f;
        arow4[j] = a;
    }
}

// ---------- O_h = P @ v_h via bf16 MFMA (k-split partials) -------------------
__global__ __launch_bounds__(256) void pv_mfma(
    const float* __restrict__ Sbuf, const ushort_t* __restrict__ vtb,
    float* __restrict__ part, int head)
{
    const int tid = threadIdx.x;
    const int wave = tid >> 6, lane = tid & 63;
    const int r = lane & 15, g = lane >> 4;
    const int row0 = blockIdx.x * 64 + wave * 16;
    const int k0base = blockIdx.y * (NT / KS);
    const int hb = head * DH;
    const ushort_t* arow = (const ushort_t*)(Sbuf + (size_t)(row0 + r) * NT);
    f32x4 acc[5] = {};
    for (int kk = 0; kk < NT / KS; kk += 32) {
        int k0 = k0base + kk;
        bf16x8 a = *(const bf16x8*)(arow + k0 + g * 8);
#pragma unroll
        for (int t = 0; t < 5; ++t) {
            int col = t * 16 + r;
            bf16x8 b = {};
            if (col < DH)
                b = *(const bf16x8*)(vtb + (size_t)(hb + col) * NT + k0 + g * 8);
            acc[t] = __builtin_amdgcn_mfma_f32_16x16x32_bf16(a, b, acc[t], 0, 0, 0);
        }
    }
    float* pp = part + (size_t)blockIdx.y * (NT * DH);
#pragma unroll
    for (int t = 0; t < 5; ++t) {
        int col = t * 16 + r;
        if (col < DH) {
#pragma unroll
            for (int j = 0; j < 4; ++j) {
                int row = row0 + g * 4 + j;
                pp[(size_t)row * DH + col] = acc[t][j];
            }
        }
    }
}

__global__ __launch_bounds__(256) void pv_reduce(
    const float* __restrict__ part, ushort_t* __restrict__ otmpb, int head)
{
    int idx = blockIdx.x * 256 + threadIdx.x;
    if (idx >= NT * DH) return;
    int row = idx / DH, col = idx - row * DH;
    float s = 0.f;
#pragma unroll
    for (int ks = 0; ks < KS; ++ks) s += part[(size_t)ks * (NT * DH) + idx];
    otmpb[(size_t)row * DM + head * DH + col] = f2b(s);
}

// ---------- pagerank power iteration (fp32, unchanged) -----------------------
__global__ __launch_bounds__(256) void init_dist(float* __restrict__ d)
{
    int t = blockIdx.x * 256 + threadIdx.x;
    if (t < NT) d[t] = 1.0f / NT;
}

__global__ __launch_bounds__(256) void power_a(
    const float* __restrict__ attn, const float* __restrict__ din,
    float* __restrict__ part)
{
    int j = blockIdx.x * 256 + threadIdx.x;
    int i0 = blockIdx.y * 128;
    float acc = 0.f;
    for (int i = i0; i < i0 + 128; ++i)
        acc += din[i] * attn[(size_t)i * NT + j];
    part[(size_t)blockIdx.y * NT + j] = acc;
}

__global__ __launch_bounds__(256) void power_b(
    const float* __restrict__ part, float* __restrict__ dout)
{
    int j = blockIdx.x * 256 + threadIdx.x;
    float acc = 0.f;
    for (int ib = 0; ib < 32; ++ib) acc += part[(size_t)ib * NT + j];
    dout[j] = acc;
}

// ---------- top-k via rank counting (jax tie rule) ---------------------------
__global__ __launch_bounds__(256) void rank_kernel(
    const float* __restrict__ imp, int* __restrict__ rank, int* __restrict__ prank)
{
    __shared__ float si[NT];
    for (int t = threadIdx.x; t < NT; t += 256) si[t] = imp[t];
    __syncthreads();
    int i = blockIdx.x * 256 + threadIdx.x;
    float mv = si[i];
    int r = 0, rp = 0;
    for (int j = 0; j < NT; ++j) {
        float vj = si[j];
        int tie_low = (vj == mv) && (j < i);
        r  += (vj > mv) || tie_low;
        rp += (vj < mv) || tie_low;
    }
    rank[i] = r;
    prank[i] = rp;
}

__global__ __launch_bounds__(256) void scatter_topk(
    const int* __restrict__ rank, const int* __restrict__ prank,
    float* __restrict__ out_imps, float* __restrict__ out_prune,
    int* __restrict__ imp_rows, int* __restrict__ prune_cols)
{
    __shared__ unsigned char fr[NT];
    __shared__ unsigned char fp[NT];
    for (int t = threadIdx.x; t < NT; t += 256) {
        fr[t] = rank[t] < KRET;
        fp[t] = prank[t] < NPR;
    }
    __syncthreads();
    int i = blockIdx.x * 256 + threadIdx.x;
    int cr = 0, cp = 0;
    for (int j = 0; j < i; ++j) { cr += fr[j]; cp += fp[j]; }
    if (fr[i]) { out_imps[cr] = (float)i; imp_rows[cr] = i; }
    if (fp[i]) { out_prune[cp] = (float)i; prune_cols[cp] = i; }
}

__global__ __launch_bounds__(256) void argmax_cols(
    const float* __restrict__ attn, const int* __restrict__ imp_rows,
    int* __restrict__ maxind)
{
    __shared__ int rows[KRET];
    for (int t = threadIdx.x; t < KRET; t += 256) rows[t] = imp_rows[t];
    __syncthreads();
    int j = blockIdx.x * 256 + threadIdx.x;
    float best = -INFINITY;
    int bi = 0;
    for (int r = 0; r < KRET; ++r) {
        float val = attn[(size_t)rows[r] * NT + j];
        if (val > best) { best = val; bi = r; }
    }
    maxind[j] = bi;
}

__global__ __launch_bounds__(256) void finalize(
    const float* __restrict__ dist, const int* __restrict__ prune_cols,
    const int* __restrict__ maxind, float* __restrict__ out_imp,
    float* __restrict__ out_simi)
{
    int t = blockIdx.x * 256 + threadIdx.x;
    if (t < NT) out_imp[t] = dist[t];
    if (t < NPR) out_simi[t] = (float)maxind[prune_cols[t]];
}

extern "C" void kernel_launch(void* const* d_in, const int* in_sizes, int n_in,
                              void* d_out, int out_size, void* d_ws, size_t ws_size,
                              hipStream_t stream)
{
    const float* x  = (const float*)d_in[0];
    const float* Wq = (const float*)d_in[1];
    const float* Wk = (const float*)d_in[2];
    const float* Wv = (const float*)d_in[3];
    const float* Wo = (const float*)d_in[4];
    const float* bo = (const float*)d_in[5];
    float* out = (float*)d_out;

    // ---- workspace layout (float units), ~200 MB with aliasing ----
    float* ws = (float*)d_ws;
    float* S    = ws;                                  // [NT][NT] fp32
    float* attn = ws + (size_t)NT * NT;                // [NT][NT] fp32
    size_t off = (size_t)NT * NT * 2;
    f16* Q0 = (f16*)(ws + off);                        // 2 planes fp16 [NT][DM]
    f16* Q1 = Q0 + (size_t)NT * DM;
    off += (size_t)NT * DM;
    f16* K0 = (f16*)(ws + off);
    f16* K1 = K0 + (size_t)NT * DM;
    off += (size_t)NT * DM;
    f16* X0 = (f16*)(ws + off);                        // later vtb + otmpb
    f16* X1 = X0 + (size_t)NT * DM;
    float* xs2_base = ws + off;
    off += (size_t)NT * DM;
    f16* T0 = (f16*)(ws + off);                        // later part
    f16* T1 = T0 + (size_t)DM * DM;
    float* wt2_base = ws + off;
    off += (size_t)DM * DM;
    ushort_t* Wslot = (ushort_t*)(ws + off); off += ((size_t)DM * DM) / 2;
    float* dist0 = ws + off; off += NT;
    float* dist1 = ws + off; off += NT;
    float* partial = ws + off; off += 32 * NT;
    int* rank      = (int*)(ws + off); off += NT;
    int* prank     = (int*)(ws + off); off += NT;
    int* imp_rows  = (int*)(ws + off); off += 2048;
    int* prune_cols= (int*)(ws + off); off += 2560;
    int* maxind    = (int*)(ws + off); off += NT;

    // aliases
    ushort_t* xb   = (ushort_t*)S;                                // bf16 x (setup)
    ushort_t* vb   = (ushort_t*)(S + (size_t)NT * DM / 2);        // bf16 v (setup)
    ushort_t* vtb  = (ushort_t*)xs2_base;                         // bf16 v^T [DM][NT]
    ushort_t* otmpb= (ushort_t*)(xs2_base + (size_t)NT * DM / 2); // bf16 attn-out
    float* part    = wt2_base;                                    // fp32 [KS][NT][DH]

    // output layout
    float* out_out   = out;
    float* out_imp   = out + (size_t)NT * DM;
    float* out_imps  = out_imp + NT;
    float* out_prune = out_imps + KRET;
    float* out_simi  = out_prune + NPR;

    // ---- setup: splits + projections ----
    split_x<<<2048, 256, 0, stream>>>(x, X0, X1, xb, NT * DM);

    dim3 gT(DM / 32, DM / 32);
    dim3 gP(DM / 64, NT / 128);
    transposeW_split<<<gT, 256, 0, stream>>>(Wq, T0, T1, DM);
    proj_split2<<<gP, 256, 0, stream>>>(X0, X1, T0, T1, Q0, Q1);
    transposeW_split<<<gT, 256, 0, stream>>>(Wk, T0, T1, DM);
    proj_split2<<<gP, 256, 0, stream>>>(X0, X1, T0, T1, K0, K1);

    transposeW_bf16<<<gT, 256, 0, stream>>>(Wv, Wslot, DM);
    gemm_bf16_lds<<<gP, 256, 0, stream>>>(xb, Wslot, nullptr, vb, 1, DM, DM);
    transposeB16<<<dim3(DM / 32, NT / 32), 256, 0, stream>>>(vb, vtb, NT, DM);

    hipMemsetAsync(attn, 0, (size_t)NT * NT * sizeof(float), stream);

    // ---- per-head attention ----
    dim3 g2(NT / 64, NT / 64);
    for (int h = 0; h < NH; ++h) {
        qk_split2<<<g2, 256, 0, stream>>>(Q0, Q1, K0, K1, S, h);
        softmax_acc<<<NT, 256, 0, stream>>>(S, attn);
        pv_mfma<<<dim3(NT / 64, KS), 256, 0, stream>>>(S, vtb, part, h);
        pv_reduce<<<(NT * DH) / 256, 256, 0, stream>>>(part, otmpb, h);
    }

    // ---- output projection ----
    transposeW_bf16<<<gT, 256, 0, stream>>>(Wo, Wslot, DM);
    gemm_bf16_lds<<<gP, 256, 0, stream>>>(otmpb, Wslot, bo, out_out, 0, DM, DM);

    // ---- pagerank + top-k (fp32, unchanged) ----
    init_dist<<<16, 256, 0, stream>>>(dist0);
    float* da = dist0;
    float* db = dist1;
    for (int it = 0; it < 5; ++it) {
        power_a<<<dim3(16, 32), 256, 0, stream>>>(attn, da, partial);
        power_b<<<16, 256, 0, stream>>>(partial, db);
        float* t = da; da = db; db = t;
    }

    rank_kernel<<<16, 256, 0, stream>>>(da, rank, prank);
    scatter_topk<<<16, 256, 0, stream>>>(rank, prank, out_imps, out_prune,
                                         imp_rows, prune_cols);
    argmax_cols<<<16, 256, 0, stream>>>(attn, imp_rows, maxind);
    finalize<<<16, 256, 0, stream>>>(da, prune_cols, maxind, out_imp, out_simi);
}